// Round 1
// baseline (153.540 us; speedup 1.0000x reference)
//
#include <hip/hip_runtime.h>

// Problem constants (from setup_inputs: x is [32,128,96,128] fp32)
#define BSZ 32
#define CC  128          // channels
#define CH  64           // C/2
#define HWN 12288        // 128*96 spatial positions
#define BPB 64           // blocks per batch for the streaming passes
#define ROWS_PER_BLOCK (HWN / BPB)   // 192

// ---------------- Pass 1: streaming stats over x ----------------
// Per row n of batch b:  q = x_row . wq_ch ;  e = exp(q)
// Accumulate: S[b,c] += e * x[b,n,c] ; Z[b] += e ; sumx[b,c] += x[b,n,c]
__global__ __launch_bounds__(256) void psa_pass1(
    const float* __restrict__ x, const float* __restrict__ wq_ch,
    float* __restrict__ S, float* __restrict__ sumx, float* __restrict__ Z)
{
    const int b    = blockIdx.x / BPB;
    const int blk  = blockIdx.x % BPB;
    const int tid  = threadIdx.x;
    const int l32  = tid & 31;      // lane within 32-lane row group
    const int slot = tid >> 5;      // 0..7 half-wave slot (8 rows in flight)

    const float4 wq = reinterpret_cast<const float4*>(wq_ch)[l32];

    float s0=0.f,s1=0.f,s2=0.f,s3=0.f;
    float a0=0.f,a1=0.f,a2=0.f,a3=0.f;
    float zacc=0.f;

    const float* xb = x + (size_t)b * (size_t)(HWN * CC);
    const int row0 = blk * ROWS_PER_BLOCK;

    for (int i = slot; i < ROWS_PER_BLOCK; i += 8) {
        const float4 xv =
            reinterpret_cast<const float4*>(xb + (size_t)(row0 + i) * CC)[l32];
        float p = xv.x*wq.x + xv.y*wq.y + xv.z*wq.z + xv.w*wq.w;
        p += __shfl_xor(p, 1);  p += __shfl_xor(p, 2);  p += __shfl_xor(p, 4);
        p += __shfl_xor(p, 8);  p += __shfl_xor(p, 16);  // reduce within 32-lane half
        const float e = __expf(p);
        if (l32 == 0) zacc += e;
        s0 += e*xv.x; s1 += e*xv.y; s2 += e*xv.z; s3 += e*xv.w;
        a0 += xv.x;   a1 += xv.y;   a2 += xv.z;   a3 += xv.w;
    }

    __shared__ float Ssh[CC];
    __shared__ float Xsh[CC];
    __shared__ float zsh;
    if (tid < CC) { Ssh[tid] = 0.f; Xsh[tid] = 0.f; }
    if (tid == 0) zsh = 0.f;
    __syncthreads();

    const int cb = l32 * 4;
    atomicAdd(&Ssh[cb+0], s0); atomicAdd(&Ssh[cb+1], s1);
    atomicAdd(&Ssh[cb+2], s2); atomicAdd(&Ssh[cb+3], s3);
    atomicAdd(&Xsh[cb+0], a0); atomicAdd(&Xsh[cb+1], a1);
    atomicAdd(&Xsh[cb+2], a2); atomicAdd(&Xsh[cb+3], a3);
    if (l32 == 0) atomicAdd(&zsh, zacc);
    __syncthreads();

    if (tid < CC) {
        atomicAdd(&S[b*CC + tid],    Ssh[tid]);
        atomicAdd(&sumx[b*CC + tid], Xsh[tid]);
    }
    if (tid == 0) atomicAdd(&Z[b], zsh);
}

// ---------------- Mid: tiny per-batch kernel (32 blocks x 128 threads) ------
// ctx_half[d] = (S . wv_ch[:,d]) / Z ; ctx[c] = ctx_half . w_ch[:,c]
// LN over c, sigmoid -> mask_ch[b,c]
// q_sp = softmax((sumx . wq_sp)/hw) over d ; wf[c] = wv_sp[c,:] . q_sp
__global__ __launch_bounds__(128) void psa_mid(
    const float* __restrict__ S, const float* __restrict__ sumx,
    const float* __restrict__ Z,
    const float* __restrict__ wv_ch, const float* __restrict__ w_ch,
    const float* __restrict__ gamma, const float* __restrict__ beta,
    const float* __restrict__ wq_sp, const float* __restrict__ wv_sp,
    float* __restrict__ mask_ch, float* __restrict__ wf)
{
    const int b = blockIdx.x;
    const int t = threadIdx.x;   // 0..127

    __shared__ float Ssh[CC], Xsh[CC], ctxh[CH], qsp[CH], red[CC];

    Ssh[t] = S[b*CC + t];
    Xsh[t] = sumx[b*CC + t];
    __syncthreads();

    if (t < CH) {
        float a = 0.f, aq = 0.f;
        for (int c = 0; c < CC; ++c) {
            a  += Ssh[c] * wv_ch[c*CH + t];
            aq += Xsh[c] * wq_sp[c*CH + t];
        }
        ctxh[t] = a / Z[b];
        qsp[t]  = aq * (1.0f / (float)HWN);
    }
    __syncthreads();

    if (t == 0) {  // 64-wide softmax, trivially serial
        float m = qsp[0];
        for (int d = 1; d < CH; ++d) m = fmaxf(m, qsp[d]);
        float ssum = 0.f;
        for (int d = 0; d < CH; ++d) { qsp[d] = __expf(qsp[d] - m); ssum += qsp[d]; }
        const float inv = 1.0f / ssum;
        for (int d = 0; d < CH; ++d) qsp[d] *= inv;
    }
    __syncthreads();

    float ctx = 0.f;
    for (int d = 0; d < CH; ++d) ctx += ctxh[d] * w_ch[d*CC + t];

    red[t] = ctx; __syncthreads();
    for (int s = 64; s > 0; s >>= 1) { if (t < s) red[t] += red[t+s]; __syncthreads(); }
    const float mu = red[0] * (1.0f / CC);
    __syncthreads();

    const float dc = ctx - mu;
    red[t] = dc * dc; __syncthreads();
    for (int s = 64; s > 0; s >>= 1) { if (t < s) red[t] += red[t+s]; __syncthreads(); }
    const float var = red[0] * (1.0f / CC);

    const float nrm = dc * rsqrtf(var + 1e-5f) * gamma[t] + beta[t];
    mask_ch[b*CC + t] = 1.0f / (1.0f + __expf(-nrm));

    float wacc = 0.f;
    for (int d = 0; d < CH; ++d) wacc += wv_sp[t*CH + d] * qsp[d];
    wf[b*CC + t] = wacc;
}

// ---------------- Pass 2: streaming output ----------------
// out[b,n,c] = x[b,n,c] * (mask_ch[b,c] + sigmoid(x_row . wf[b,:]))
__global__ __launch_bounds__(256) void psa_pass2(
    const float* __restrict__ x, const float* __restrict__ mask_ch,
    const float* __restrict__ wf, float* __restrict__ out)
{
    const int b    = blockIdx.x / BPB;
    const int blk  = blockIdx.x % BPB;
    const int tid  = threadIdx.x;
    const int l32  = tid & 31;
    const int slot = tid >> 5;

    const float4 m4 = reinterpret_cast<const float4*>(mask_ch + b*CC)[l32];
    const float4 w4 = reinterpret_cast<const float4*>(wf + b*CC)[l32];

    const float* xb = x   + (size_t)b * (size_t)(HWN * CC);
    float*       ob = out + (size_t)b * (size_t)(HWN * CC);
    const int row0 = blk * ROWS_PER_BLOCK;

    for (int i = slot; i < ROWS_PER_BLOCK; i += 8) {
        const size_t off = (size_t)(row0 + i) * CC;
        const float4 xv = reinterpret_cast<const float4*>(xb + off)[l32];
        float p = xv.x*w4.x + xv.y*w4.y + xv.z*w4.z + xv.w*w4.w;
        p += __shfl_xor(p, 1);  p += __shfl_xor(p, 2);  p += __shfl_xor(p, 4);
        p += __shfl_xor(p, 8);  p += __shfl_xor(p, 16);
        const float g = 1.0f / (1.0f + __expf(-p));
        float4 o;
        o.x = xv.x * (m4.x + g);
        o.y = xv.y * (m4.y + g);
        o.z = xv.z * (m4.z + g);
        o.w = xv.w * (m4.w + g);
        reinterpret_cast<float4*>(ob + off)[l32] = o;
    }
}

extern "C" void kernel_launch(void* const* d_in, const int* in_sizes, int n_in,
                              void* d_out, int out_size, void* d_ws, size_t ws_size,
                              hipStream_t stream) {
    const float* x     = (const float*)d_in[0];
    const float* wq_ch = (const float*)d_in[1];
    const float* wv_ch = (const float*)d_in[2];
    const float* w_ch  = (const float*)d_in[3];
    const float* gamma = (const float*)d_in[4];
    const float* beta  = (const float*)d_in[5];
    const float* wq_sp = (const float*)d_in[6];
    const float* wv_sp = (const float*)d_in[7];
    float* out = (float*)d_out;

    // workspace layout (floats): S[32*128] | sumx[32*128] | Z[32] | mask[32*128] | wf[32*128]
    float* ws   = (float*)d_ws;
    float* S    = ws;
    float* sumx = ws + BSZ*CC;
    float* Z    = ws + 2*BSZ*CC;
    float* mask = ws + 2*BSZ*CC + BSZ;
    float* wf   = ws + 3*BSZ*CC + BSZ;

    // zero the atomic accumulators (ws is poisoned 0xAA and not re-poisoned)
    hipMemsetAsync(d_ws, 0, (size_t)(2*BSZ*CC + BSZ) * sizeof(float), stream);

    psa_pass1<<<BSZ*BPB, 256, 0, stream>>>(x, wq_ch, S, sumx, Z);
    psa_mid  <<<BSZ,     128, 0, stream>>>(S, sumx, Z, wv_ch, w_ch, gamma, beta,
                                           wq_sp, wv_sp, mask, wf);
    psa_pass2<<<BSZ*BPB, 256, 0, stream>>>(x, mask, wf, out);
}

// Round 2
// 126.612 us; speedup vs baseline: 1.2127x; 1.2127x over previous
//
#include <hip/hip_runtime.h>

// Problem constants (x is [32,128,96,128] fp32)
#define BSZ 32
#define CC  128          // channels
#define CH  64           // C/2
#define HWN 12288        // 128*96 spatial positions
#define BPB 64           // blocks per batch for the streaming passes
#define ROWS_PER_BLOCK (HWN / BPB)   // 192

using f4 = __attribute__((ext_vector_type(4))) float;

// ---------------- Pass 1: streaming stats over x ----------------
// Per row n of batch b:  q = x_row . wq_ch ;  e = exp(q)
// Per-block partials (no atomics, no memset needed):
//   pS[b,blk,c]  = sum_rows e * x[...,c]
//   pX[b,blk,c]  = sum_rows x[...,c]
//   pZ[b,blk]    = sum_rows e
__global__ __launch_bounds__(256) void psa_pass1(
    const float* __restrict__ x, const float* __restrict__ wq_ch,
    float* __restrict__ pS, float* __restrict__ pX, float* __restrict__ pZ)
{
    const int b    = blockIdx.x / BPB;
    const int blk  = blockIdx.x % BPB;
    const int tid  = threadIdx.x;
    const int l32  = tid & 31;      // lane within 32-lane row group
    const int slot = tid >> 5;      // 0..7 (8 rows in flight per block)

    const f4 wq = reinterpret_cast<const f4*>(wq_ch)[l32];

    float s0=0.f,s1=0.f,s2=0.f,s3=0.f;
    float a0=0.f,a1=0.f,a2=0.f,a3=0.f;
    float zacc=0.f;

    const float* xb = x + (size_t)b * (size_t)(HWN * CC);
    const int row0 = blk * ROWS_PER_BLOCK;

    for (int i = slot; i < ROWS_PER_BLOCK; i += 8) {
        const f4 xv = reinterpret_cast<const f4*>(xb + (size_t)(row0 + i) * CC)[l32];
        float p = xv.x*wq.x + xv.y*wq.y + xv.z*wq.z + xv.w*wq.w;
        p += __shfl_xor(p, 1);  p += __shfl_xor(p, 2);  p += __shfl_xor(p, 4);
        p += __shfl_xor(p, 8);  p += __shfl_xor(p, 16);  // 32-lane row reduce
        const float e = __expf(p);
        if (l32 == 0) zacc += e;
        s0 += e*xv.x; s1 += e*xv.y; s2 += e*xv.z; s3 += e*xv.w;
        a0 += xv.x;   a1 += xv.y;   a2 += xv.z;   a3 += xv.w;
    }

    __shared__ float Ssh[CC];
    __shared__ float Xsh[CC];
    __shared__ float zsh;
    if (tid < CC) { Ssh[tid] = 0.f; Xsh[tid] = 0.f; }
    if (tid == 0) zsh = 0.f;
    __syncthreads();

    const int cb = l32 * 4;
    atomicAdd(&Ssh[cb+0], s0); atomicAdd(&Ssh[cb+1], s1);
    atomicAdd(&Ssh[cb+2], s2); atomicAdd(&Ssh[cb+3], s3);
    atomicAdd(&Xsh[cb+0], a0); atomicAdd(&Xsh[cb+1], a1);
    atomicAdd(&Xsh[cb+2], a2); atomicAdd(&Xsh[cb+3], a3);
    if (l32 == 0) atomicAdd(&zsh, zacc);
    __syncthreads();

    const size_t base = (size_t)(b * BPB + blk) * CC;
    if (tid < CC) {
        pS[base + tid] = Ssh[tid];
        pX[base + tid] = Xsh[tid];
    }
    if (tid == 0) pZ[b * BPB + blk] = zsh;
}

// ---------------- Mid: tiny per-batch kernel (32 blocks x 128 threads) ------
__global__ __launch_bounds__(128) void psa_mid(
    const float* __restrict__ pS, const float* __restrict__ pX,
    const float* __restrict__ pZ,
    const float* __restrict__ wv_ch, const float* __restrict__ w_ch,
    const float* __restrict__ gamma, const float* __restrict__ beta,
    const float* __restrict__ wq_sp, const float* __restrict__ wv_sp,
    float* __restrict__ mask_ch, float* __restrict__ wf)
{
    const int b = blockIdx.x;
    const int t = threadIdx.x;   // 0..127

    __shared__ float Ssh[CC], Xsh[CC], ctxh[CH], qsp[CH], zsh, red2[2];

    // reduce the 64 per-block partials (coalesced across t)
    {
        const float* pSb = pS + (size_t)b * BPB * CC;
        const float* pXb = pX + (size_t)b * BPB * CC;
        float s = 0.f, a = 0.f;
        #pragma unroll
        for (int k = 0; k < BPB; ++k) {
            s += pSb[(size_t)k * CC + t];
            a += pXb[(size_t)k * CC + t];
        }
        Ssh[t] = s; Xsh[t] = a;
    }
    if (t < 64) {   // wave 0 reduces Z
        float z = pZ[b * BPB + t];
        z += __shfl_xor(z, 1); z += __shfl_xor(z, 2);  z += __shfl_xor(z, 4);
        z += __shfl_xor(z, 8); z += __shfl_xor(z, 16); z += __shfl_xor(z, 32);
        if (t == 0) zsh = z;
    }
    __syncthreads();

    if (t < CH) {
        float a = 0.f, aq = 0.f;
        #pragma unroll
        for (int c = 0; c < CC; ++c) {
            a  += Ssh[c] * wv_ch[c*CH + t];
            aq += Xsh[c] * wq_sp[c*CH + t];
        }
        ctxh[t] = a / zsh;
        // spatial softmax input, then wave-parallel softmax (t<64 = wave 0)
        float q = aq * (1.0f / (float)HWN);
        float m = q;
        m = fmaxf(m, __shfl_xor(m, 1));  m = fmaxf(m, __shfl_xor(m, 2));
        m = fmaxf(m, __shfl_xor(m, 4));  m = fmaxf(m, __shfl_xor(m, 8));
        m = fmaxf(m, __shfl_xor(m, 16)); m = fmaxf(m, __shfl_xor(m, 32));
        float e = __expf(q - m);
        float sum = e;
        sum += __shfl_xor(sum, 1);  sum += __shfl_xor(sum, 2);
        sum += __shfl_xor(sum, 4);  sum += __shfl_xor(sum, 8);
        sum += __shfl_xor(sum, 16); sum += __shfl_xor(sum, 32);
        qsp[t] = e / sum;
    }
    __syncthreads();

    float ctx = 0.f;
    #pragma unroll
    for (int d = 0; d < CH; ++d) ctx += ctxh[d] * w_ch[d*CC + t];

    // LN over 128 channels: per-wave shfl reduce + 2-way LDS combine
    const int wid = t >> 6;
    {
        float r = ctx;
        r += __shfl_xor(r, 1);  r += __shfl_xor(r, 2);  r += __shfl_xor(r, 4);
        r += __shfl_xor(r, 8);  r += __shfl_xor(r, 16); r += __shfl_xor(r, 32);
        if ((t & 63) == 0) red2[wid] = r;
    }
    __syncthreads();
    const float mu = (red2[0] + red2[1]) * (1.0f / CC);
    __syncthreads();
    const float dc = ctx - mu;
    {
        float r = dc * dc;
        r += __shfl_xor(r, 1);  r += __shfl_xor(r, 2);  r += __shfl_xor(r, 4);
        r += __shfl_xor(r, 8);  r += __shfl_xor(r, 16); r += __shfl_xor(r, 32);
        if ((t & 63) == 0) red2[wid] = r;
    }
    __syncthreads();
    const float var = (red2[0] + red2[1]) * (1.0f / CC);

    const float nrm = dc * rsqrtf(var + 1e-5f) * gamma[t] + beta[t];
    mask_ch[b*CC + t] = 1.0f / (1.0f + __expf(-nrm));

    float wacc = 0.f;
    #pragma unroll
    for (int d = 0; d < CH; ++d) wacc += wv_sp[t*CH + d] * qsp[d];
    wf[b*CC + t] = wacc;
}

// ---------------- Pass 2: streaming output ----------------
// out[b,n,c] = x[b,n,c] * (mask_ch[b,c] + sigmoid(x_row . wf[b,:]))
__global__ __launch_bounds__(256) void psa_pass2(
    const float* __restrict__ x, const float* __restrict__ mask_ch,
    const float* __restrict__ wf, float* __restrict__ out)
{
    const int b    = blockIdx.x / BPB;
    const int blk  = blockIdx.x % BPB;
    const int tid  = threadIdx.x;
    const int l32  = tid & 31;
    const int slot = tid >> 5;

    const f4 m4 = reinterpret_cast<const f4*>(mask_ch + b*CC)[l32];
    const f4 w4 = reinterpret_cast<const f4*>(wf + b*CC)[l32];

    const float* xb = x   + (size_t)b * (size_t)(HWN * CC);
    float*       ob = out + (size_t)b * (size_t)(HWN * CC);
    const int row0 = blk * ROWS_PER_BLOCK;

    for (int i = slot; i < ROWS_PER_BLOCK; i += 8) {
        const size_t off = (size_t)(row0 + i) * CC;
        const f4 xv = reinterpret_cast<const f4*>(xb + off)[l32];
        float p = xv.x*w4.x + xv.y*w4.y + xv.z*w4.z + xv.w*w4.w;
        p += __shfl_xor(p, 1);  p += __shfl_xor(p, 2);  p += __shfl_xor(p, 4);
        p += __shfl_xor(p, 8);  p += __shfl_xor(p, 16);
        const float g = 1.0f / (1.0f + __expf(-p));
        f4 o;
        o.x = xv.x * (m4.x + g);
        o.y = xv.y * (m4.y + g);
        o.z = xv.z * (m4.z + g);
        o.w = xv.w * (m4.w + g);
        // non-temporal: don't let the out stream evict x from L3
        __builtin_nontemporal_store(o, reinterpret_cast<f4*>(ob + off) + l32);
    }
}

extern "C" void kernel_launch(void* const* d_in, const int* in_sizes, int n_in,
                              void* d_out, int out_size, void* d_ws, size_t ws_size,
                              hipStream_t stream) {
    const float* x     = (const float*)d_in[0];
    const float* wq_ch = (const float*)d_in[1];
    const float* wv_ch = (const float*)d_in[2];
    const float* w_ch  = (const float*)d_in[3];
    const float* gamma = (const float*)d_in[4];
    const float* beta  = (const float*)d_in[5];
    const float* wq_sp = (const float*)d_in[6];
    const float* wv_sp = (const float*)d_in[7];
    float* out = (float*)d_out;

    // workspace (floats): pS[32*64*128] | pX[32*64*128] | pZ[32*64] | mask[32*128] | wf[32*128]
    float* ws   = (float*)d_ws;
    float* pS   = ws;
    float* pX   = pS + (size_t)BSZ*BPB*CC;
    float* pZ   = pX + (size_t)BSZ*BPB*CC;
    float* mask = pZ + BSZ*BPB;
    float* wf   = mask + BSZ*CC;

    psa_pass1<<<BSZ*BPB, 256, 0, stream>>>(x, wq_ch, pS, pX, pZ);
    psa_mid  <<<BSZ,     128, 0, stream>>>(pS, pX, pZ, wv_ch, w_ch, gamma, beta,
                                           wq_sp, wv_sp, mask, wf);
    psa_pass2<<<BSZ*BPB, 256, 0, stream>>>(x, mask, wf, out);
}